// Round 9
// baseline (3587.700 us; speedup 1.0000x reference)
//
#include <hip/hip_runtime.h>
#include <math.h>

#define DEV_INLINE __device__ __forceinline__

static constexpr int Bn = 64;     // batch
static constexpr int Tn = 512;    // time
static constexpr int En = 512;    // embed
static constexpr int Hn = 1024;   // hidden
static constexpr int Cn = 256;    // classes
static constexpr int Gn = 4 * Hn; // 4096 gates

typedef float v4f __attribute__((ext_vector_type(4)));
typedef _Float16 v8h __attribute__((ext_vector_type(8)));

DEV_INLINE float sigmoidf_(float v) { return 1.f / (1.f + __expf(-v)); }

// ---------------------------------------------------------------------------
// fp32 tiled GEMM:  C[M,N] = A[M,K] * B[N,K]^T + bias1[n] (+bias2[n])
// (used for proj = embed @ W_ih^T + b_ih + b_hh)
// ---------------------------------------------------------------------------
__global__ __launch_bounds__(256) void gemm_tt(
    const float* __restrict__ A, const float* __restrict__ Bm,
    const float* __restrict__ bias1, const float* __restrict__ bias2,
    float* __restrict__ Cm, int M, int N, int K)
{
  constexpr int KC = 32;
  __shared__ float As[KC][68];
  __shared__ float Bs[KC][68];
  const int tid = threadIdx.x;
  const int tx = tid & 15, ty = tid >> 4;
  const int m0 = blockIdx.x * 64, n0 = blockIdx.y * 64;

  float acc[4][4] = {};

  for (int k0 = 0; k0 < K; k0 += KC) {
    __syncthreads();
    #pragma unroll
    for (int j = 0; j < 2; ++j) {
      int f = tid + j * 256;
      int row = f >> 3;
      int c4 = f & 7;
      float4 va = *reinterpret_cast<const float4*>(&A[(size_t)(m0 + row) * K + k0 + c4 * 4]);
      As[c4 * 4 + 0][row] = va.x; As[c4 * 4 + 1][row] = va.y;
      As[c4 * 4 + 2][row] = va.z; As[c4 * 4 + 3][row] = va.w;
      float4 vb = *reinterpret_cast<const float4*>(&Bm[(size_t)(n0 + row) * K + k0 + c4 * 4]);
      Bs[c4 * 4 + 0][row] = vb.x; Bs[c4 * 4 + 1][row] = vb.y;
      Bs[c4 * 4 + 2][row] = vb.z; Bs[c4 * 4 + 3][row] = vb.w;
    }
    __syncthreads();
    #pragma unroll
    for (int k = 0; k < KC; ++k) {
      float4 a4 = *reinterpret_cast<const float4*>(&As[k][ty * 4]);
      float4 b4 = *reinterpret_cast<const float4*>(&Bs[k][tx * 4]);
      float ar[4] = {a4.x, a4.y, a4.z, a4.w};
      float br[4] = {b4.x, b4.y, b4.z, b4.w};
      #pragma unroll
      for (int i = 0; i < 4; ++i)
        #pragma unroll
        for (int j = 0; j < 4; ++j)
          acc[i][j] += ar[i] * br[j];
    }
  }

  #pragma unroll
  for (int j = 0; j < 4; ++j) {
    int n = n0 + tx * 4 + j;
    float bb = bias1[n];
    if (bias2) bb += bias2[n];
    #pragma unroll
    for (int i = 0; i < 4; ++i)
      Cm[(size_t)(m0 + ty * 4 + i) * N + n] = acc[i][j] + bb;
  }
}

// ---------------------------------------------------------------------------
// FC GEMM reading fp16 A (hs16, layout [t][b][h], row index m = t*64+b),
// writing out[b][t][c] fp32.  out = A @ fc_W^T + fc_b.
// ---------------------------------------------------------------------------
__global__ __launch_bounds__(256) void gemm_fc(
    const _Float16* __restrict__ A,   // [32768][1024] fp16
    const float* __restrict__ Bm,     // fc_W [256][1024]
    const float* __restrict__ bias,   // fc_b [256]
    float* __restrict__ out)          // [64][512][256]
{
  constexpr int KC = 32;
  __shared__ float As[KC][68];
  __shared__ float Bs[KC][68];
  const int tid = threadIdx.x;
  const int tx = tid & 15, ty = tid >> 4;
  const int m0 = blockIdx.x * 64, n0 = blockIdx.y * 64;

  float acc[4][4] = {};

  for (int k0 = 0; k0 < Hn; k0 += KC) {
    __syncthreads();
    {
      int row = tid >> 2, c8 = tid & 3;     // 64 rows x 4 chunks of 8 halves
      v8h va = *(const v8h*)(A + (size_t)(m0 + row) * Hn + k0 + c8 * 8);
      #pragma unroll
      for (int e = 0; e < 8; ++e) As[c8 * 8 + e][row] = (float)va[e];
    }
    #pragma unroll
    for (int j = 0; j < 2; ++j) {
      int f = tid + j * 256, row = f >> 3, c4 = f & 7;
      float4 vb = *reinterpret_cast<const float4*>(&Bm[(size_t)(n0 + row) * Hn + k0 + c4 * 4]);
      Bs[c4 * 4 + 0][row] = vb.x; Bs[c4 * 4 + 1][row] = vb.y;
      Bs[c4 * 4 + 2][row] = vb.z; Bs[c4 * 4 + 3][row] = vb.w;
    }
    __syncthreads();
    #pragma unroll
    for (int k = 0; k < KC; ++k) {
      float4 a4 = *reinterpret_cast<const float4*>(&As[k][ty * 4]);
      float4 b4 = *reinterpret_cast<const float4*>(&Bs[k][tx * 4]);
      float ar[4] = {a4.x, a4.y, a4.z, a4.w};
      float br[4] = {b4.x, b4.y, b4.z, b4.w};
      #pragma unroll
      for (int i = 0; i < 4; ++i)
        #pragma unroll
        for (int j = 0; j < 4; ++j)
          acc[i][j] += ar[i] * br[j];
    }
  }

  #pragma unroll
  for (int j = 0; j < 4; ++j) {
    int n = n0 + tx * 4 + j;
    float bb = bias[n];
    #pragma unroll
    for (int i = 0; i < 4; ++i) {
      int m = m0 + ty * 4 + i;
      int b = m & 63, t = m >> 6;
      out[((size_t)b * Tn + t) * Cn + n] = acc[i][j] + bb;
    }
  }
}

// ---------------------------------------------------------------------------
// Dual-stream MFMA W-stationary persistent LSTM. 64 blocks x 512 threads.
// Block (pair=bid>>5, hg=bid&31) runs TWO independent recurrences:
// bg = 2*pair+s for s=0,1 (batches [bg*16,+16)), h-cols [hg*32,+32) — same
// W registers serve both streams. While stream A's h/flag propagate through
// the fabric, the block computes stream B — exchange latency leaves the
// critical path. Exchange protocol identical to the verified R7 kernel:
// h stores + flag store sc0 sc1 write-through (wave-0, vmcnt-drained before
// flag), consumers poll per-(t,bg) 128B flag lines with 32 sc0 sc1 lanes,
// then stage once. LDS (hT/gbuf/hstage) time-shared serially by the
// streams; ordering by the existing data-dep + __syncthreads chain.
// Per-(t) exact-match flags, memset'd each call: replay/poison/placement
// safe; any dispatch order terminates (no liveness assumptions).
// ---------------------------------------------------------------------------
__global__ __launch_bounds__(512, 2) void lstm_mfma(
    const int* __restrict__ x,        // [B, T]
    const float* __restrict__ Whh,    // [4H, H] fp32
    const float* __restrict__ proj,   // [C, 4H] incl. both biases
    _Float16* __restrict__ hs16,      // [T, B, H] fp16 exchange + FC input
    int* __restrict__ flags)          // [Tn][4][32] dwords (128B per line)
{
  __shared__ __align__(16) char hT[32768];     // A-tile, fragment-linear
  __shared__ float gbuf[128 * 21];             // gate exchange, stride 21
  __shared__ _Float16 hstage[512];             // 16 x 32 fp16 h repack

  const int tid = threadIdx.x;
  const int bid = blockIdx.x;
  const int pair = bid >> 5, hg = bid & 31;

  const int w = tid >> 6, l = tid & 63;
  const int q = w >> 2, g = w & 3;
  const int mrow = l & 15;                     // B col in tile / A row
  const int kseg = l >> 4;                     // k-segment 0..3

  // ---- one-time W preload: fp32 -> fp16 fragments (shared by both streams)
  v8h wv[32];
  {
    const float* wr = Whh + (size_t)(g * Hn + hg * 32 + q * 16 + mrow) * Hn + kseg * 8;
    #pragma unroll
    for (int kk = 0; kk < 32; ++kk) {
      const float* p = wr + kk * 32;
      float4 f0 = *(const float4*)p, f1 = *(const float4*)(p + 4);
      v8h h8;
      h8[0] = (_Float16)f0.x; h8[1] = (_Float16)f0.y;
      h8[2] = (_Float16)f0.z; h8[3] = (_Float16)f0.w;
      h8[4] = (_Float16)f1.x; h8[5] = (_Float16)f1.y;
      h8[6] = (_Float16)f1.z; h8[7] = (_Float16)f1.w;
      wv[kk] = h8;
    }
  }

  // elementwise mapping: thread owns (batch eb, hcol ehc)
  const int eb = tid >> 5, ehc = tid & 31;
  const int* xp0 = x + (size_t)((pair * 2 + 0) * 16 + eb) * Tn;
  const int* xp1 = x + (size_t)((pair * 2 + 1) * 16 + eb) * Tn;
  float cst[2] = {0.f, 0.f};

  // staging: dest = hT + tid*16 + i*8192 (linear, conflict-free); source
  // offset pre-swizzled so dest order is MFMA fragment order [kk][kseg][mrow]
  const int srcoff = (tid & 15) * 2048 + ((tid >> 4) & 3) * 16 + (tid >> 6) * 64;

  for (int t = 0; t < Tn; ++t) {
    #pragma unroll
    for (int s = 0; s < 2; ++s) {
      const int bg = pair * 2 + s;
      const int b0 = bg * 16;
      const int cls = (s == 0) ? xp0[t] : xp1[t];
      // proj prefetch: issued before the poll, lands during the wait
      const float* pb = proj + (size_t)cls * Gn + hg * 32 + ehc;
      float p0 = pb[0], p1 = pb[Hn], p2 = pb[2 * Hn], p3 = pb[3 * Hn];

      if (t > 0) {
        // ---- wait: 32 lanes poll the (t-1, bg) flag line
        if (tid < 32) {
          const int* fp = flags + ((size_t)(t - 1) * 4 + bg) * 32 + tid;
          int v;
          do {
            asm volatile(
              "global_load_dword %0, %1, off sc0 sc1\n\t"
              "s_waitcnt vmcnt(0)"
              : "=v"(v) : "v"(fp) : "memory");
          } while (v == 0);
        }
        __syncthreads();

        // ---- stage h[t-1] (32KB): 4x 16B coherent loads, linear LDS dest
        const char* src = (const char*)(hs16 + ((size_t)(t - 1) * Bn + b0) * Hn);
        const char* s0 = src + srcoff;
        v4f r0, r1, r2, r3;
        asm volatile(
          "global_load_dwordx4 %0, %4, off sc0 sc1\n\t"
          "global_load_dwordx4 %1, %5, off sc0 sc1\n\t"
          "global_load_dwordx4 %2, %6, off sc0 sc1\n\t"
          "global_load_dwordx4 %3, %7, off sc0 sc1\n\t"
          "s_waitcnt vmcnt(0)"
          : "=&v"(r0), "=&v"(r1), "=&v"(r2), "=&v"(r3)
          : "v"(s0), "v"(s0 + 512), "v"(s0 + 1024), "v"(s0 + 1536)
          : "memory");
        *(v4f*)(hT + tid * 16 +     0) = r0;
        *(v4f*)(hT + tid * 16 +  8192) = r1;
        *(v4f*)(hT + tid * 16 + 16384) = r2;
        *(v4f*)(hT + tid * 16 + 24576) = r3;
      }
      __syncthreads();

      v4f acc0 = {0.f, 0.f, 0.f, 0.f};
      v4f acc1 = {0.f, 0.f, 0.f, 0.f};
      if (t > 0) {
        #pragma unroll
        for (int kk = 0; kk < 32; kk += 2) {
          v8h a0 = *(const v8h*)(hT + kk * 1024 + l * 16);       // linear
          v8h a1 = *(const v8h*)(hT + (kk + 1) * 1024 + l * 16);
          acc0 = __builtin_amdgcn_mfma_f32_16x16x32_f16(a0, wv[kk], acc0, 0, 0, 0);
          acc1 = __builtin_amdgcn_mfma_f32_16x16x32_f16(a1, wv[kk + 1], acc1, 0, 0, 0);
        }
      }

      // D frag: col = l&15 (hc within q-half), row = 4*kseg + r (batch)
      #pragma unroll
      for (int r = 0; r < 4; ++r)
        gbuf[(g * 32 + q * 16 + mrow) * 21 + kseg * 4 + r] = acc0[r] + acc1[r];
      __syncthreads();

      // elementwise: all 512 threads, one (batch, hc) each
      {
        float g0 = gbuf[(0 * 32 + ehc) * 21 + eb] + p0;
        float g1 = gbuf[(1 * 32 + ehc) * 21 + eb] + p1;
        float g2 = gbuf[(2 * 32 + ehc) * 21 + eb] + p2;
        float g3 = gbuf[(3 * 32 + ehc) * 21 + eb] + p3;
        float ig = sigmoidf_(g0), fg = sigmoidf_(g1);
        float gg = tanhf(g2),     og = sigmoidf_(g3);
        cst[s] = fg * cst[s] + ig * gg;
        hstage[eb * 32 + ehc] = (_Float16)(og * tanhf(cst[s]));
      }
      __syncthreads();

      if (tid < 64) {
        // 16B coherent stores; all in wave 0 -> its vmcnt(0) drains them
        // before lane 0 publishes the flag (per-wave counter ordering).
        const int b = tid >> 2, part = tid & 3;
        v4f v = *(const v4f*)(hstage + b * 32 + part * 8);
        _Float16* dp = hs16 + ((size_t)t * Bn + b0 + b) * Hn + hg * 32 + part * 8;
        asm volatile(
          "global_store_dwordx4 %0, %1, off sc0 sc1\n\t"
          "s_waitcnt vmcnt(0)"
          :: "v"(dp), "v"(v) : "memory");
        if (tid == 0) {
          int one = 1;
          int* fq = flags + ((size_t)t * 4 + bg) * 32 + hg;
          asm volatile(
            "global_store_dword %0, %1, off sc0 sc1\n\t"
            "s_waitcnt vmcnt(0)"
            :: "v"(fq), "v"(one) : "memory");
        }
      }
      // hT/hstage reuse by the next stream/step is ordered by the poll +
      // __syncthreads chain (MFMA reads precede gbuf writes by data dep).
    }
  }
}

// ---------------------------------------------------------------------------
extern "C" void kernel_launch(void* const* d_in, const int* in_sizes, int n_in,
                              void* d_out, int out_size, void* d_ws, size_t ws_size,
                              hipStream_t stream) {
  const int*   x     = (const int*)  d_in[0];
  const float* embed = (const float*)d_in[1];
  const float* Wih   = (const float*)d_in[2];
  const float* Whh   = (const float*)d_in[3];
  const float* bih   = (const float*)d_in[4];
  const float* bhh   = (const float*)d_in[5];
  const float* fcW   = (const float*)d_in[6];
  const float* fcb   = (const float*)d_in[7];
  float* out = (float*)d_out;

  char* ws = (char*)d_ws;
  const size_t ctlBytes  = (size_t)Tn * 4 * 32 * 4;                    // 256 KB flags
  const size_t projBytes = (size_t)Cn * Gn * sizeof(float);            // 4 MB
  const size_t hsBytes   = (size_t)Tn * Bn * Hn * sizeof(_Float16);    // 64 MB
  const size_t need = ctlBytes + projBytes + hsBytes;
  if (ws_size < need) {
    hipMemsetAsync(d_out, 0, (size_t)out_size * sizeof(float), stream);
    return;
  }
  float*     proj = (float*)(ws + ctlBytes);
  _Float16*  hs16 = (_Float16*)(ws + ctlBytes + projBytes);

  // zero flags every call (graph-capture-safe async memset)
  hipMemsetAsync(d_ws, 0, ctlBytes, stream);

  // 1) proj[cls, 4H] = embed[cls,:] @ W_ih^T + b_ih + b_hh
  dim3 g1(Cn / 64, Gn / 64);   // (4, 64)
  gemm_tt<<<g1, 256, 0, stream>>>(embed, Wih, bih, bhh, proj, Cn, Gn, En);

  // 2) dual-stream MFMA W-stationary persistent recurrence
  lstm_mfma<<<64, 512, 0, stream>>>(x, Whh, proj, hs16, (int*)d_ws);

  // 3) out[b,t,:] = hs16[t,b,:] @ fc_W^T + fc_b
  dim3 g3((Bn * Tn) / 64, Cn / 64);  // (512, 4)
  gemm_fc<<<g3, 256, 0, stream>>>(hs16, fcW, fcb, out);
}

// Round 10
// 2863.343 us; speedup vs baseline: 1.2530x; 1.2530x over previous
//
#include <hip/hip_runtime.h>
#include <math.h>

#define DEV_INLINE __device__ __forceinline__

static constexpr int Bn = 64;     // batch
static constexpr int Tn = 512;    // time
static constexpr int En = 512;    // embed
static constexpr int Hn = 1024;   // hidden
static constexpr int Cn = 256;    // classes
static constexpr int Gn = 4 * Hn; // 4096 gates

typedef float v4f __attribute__((ext_vector_type(4)));
typedef unsigned int v4u __attribute__((ext_vector_type(4)));
typedef _Float16 v8h __attribute__((ext_vector_type(8)));

DEV_INLINE float sigmoidf_(float v) { return 1.f / (1.f + __expf(-v)); }

// ---------------------------------------------------------------------------
// fp32 tiled GEMM:  C[M,N] = A[M,K] * B[N,K]^T + bias1[n] (+bias2[n])
// (used for proj = embed @ W_ih^T + b_ih + b_hh)
// ---------------------------------------------------------------------------
__global__ __launch_bounds__(256) void gemm_tt(
    const float* __restrict__ A, const float* __restrict__ Bm,
    const float* __restrict__ bias1, const float* __restrict__ bias2,
    float* __restrict__ Cm, int M, int N, int K)
{
  constexpr int KC = 32;
  __shared__ float As[KC][68];
  __shared__ float Bs[KC][68];
  const int tid = threadIdx.x;
  const int tx = tid & 15, ty = tid >> 4;
  const int m0 = blockIdx.x * 64, n0 = blockIdx.y * 64;

  float acc[4][4] = {};

  for (int k0 = 0; k0 < K; k0 += KC) {
    __syncthreads();
    #pragma unroll
    for (int j = 0; j < 2; ++j) {
      int f = tid + j * 256;
      int row = f >> 3;
      int c4 = f & 7;
      float4 va = *reinterpret_cast<const float4*>(&A[(size_t)(m0 + row) * K + k0 + c4 * 4]);
      As[c4 * 4 + 0][row] = va.x; As[c4 * 4 + 1][row] = va.y;
      As[c4 * 4 + 2][row] = va.z; As[c4 * 4 + 3][row] = va.w;
      float4 vb = *reinterpret_cast<const float4*>(&Bm[(size_t)(n0 + row) * K + k0 + c4 * 4]);
      Bs[c4 * 4 + 0][row] = vb.x; Bs[c4 * 4 + 1][row] = vb.y;
      Bs[c4 * 4 + 2][row] = vb.z; Bs[c4 * 4 + 3][row] = vb.w;
    }
    __syncthreads();
    #pragma unroll
    for (int k = 0; k < KC; ++k) {
      float4 a4 = *reinterpret_cast<const float4*>(&As[k][ty * 4]);
      float4 b4 = *reinterpret_cast<const float4*>(&Bs[k][tx * 4]);
      float ar[4] = {a4.x, a4.y, a4.z, a4.w};
      float br[4] = {b4.x, b4.y, b4.z, b4.w};
      #pragma unroll
      for (int i = 0; i < 4; ++i)
        #pragma unroll
        for (int j = 0; j < 4; ++j)
          acc[i][j] += ar[i] * br[j];
    }
  }

  #pragma unroll
  for (int j = 0; j < 4; ++j) {
    int n = n0 + tx * 4 + j;
    float bb = bias1[n];
    if (bias2) bb += bias2[n];
    #pragma unroll
    for (int i = 0; i < 4; ++i)
      Cm[(size_t)(m0 + ty * 4 + i) * N + n] = acc[i][j] + bb;
  }
}

// ---------------------------------------------------------------------------
// FC GEMM reading fp16 A (hs16, layout [t][b][h], row index m = t*64+b),
// writing out[b][t][c] fp32.  out = A @ fc_W^T + fc_b.
// ---------------------------------------------------------------------------
__global__ __launch_bounds__(256) void gemm_fc(
    const _Float16* __restrict__ A,   // [32768][1024] fp16
    const float* __restrict__ Bm,     // fc_W [256][1024]
    const float* __restrict__ bias,   // fc_b [256]
    float* __restrict__ out)          // [64][512][256]
{
  constexpr int KC = 32;
  __shared__ float As[KC][68];
  __shared__ float Bs[KC][68];
  const int tid = threadIdx.x;
  const int tx = tid & 15, ty = tid >> 4;
  const int m0 = blockIdx.x * 64, n0 = blockIdx.y * 64;

  float acc[4][4] = {};

  for (int k0 = 0; k0 < Hn; k0 += KC) {
    __syncthreads();
    {
      int row = tid >> 2, c8 = tid & 3;     // 64 rows x 4 chunks of 8 halves
      v8h va = *(const v8h*)(A + (size_t)(m0 + row) * Hn + k0 + c8 * 8);
      #pragma unroll
      for (int e = 0; e < 8; ++e) As[c8 * 8 + e][row] = (float)va[e];
    }
    #pragma unroll
    for (int j = 0; j < 2; ++j) {
      int f = tid + j * 256, row = f >> 3, c4 = f & 7;
      float4 vb = *reinterpret_cast<const float4*>(&Bm[(size_t)(n0 + row) * Hn + k0 + c4 * 4]);
      Bs[c4 * 4 + 0][row] = vb.x; Bs[c4 * 4 + 1][row] = vb.y;
      Bs[c4 * 4 + 2][row] = vb.z; Bs[c4 * 4 + 3][row] = vb.w;
    }
    __syncthreads();
    #pragma unroll
    for (int k = 0; k < KC; ++k) {
      float4 a4 = *reinterpret_cast<const float4*>(&As[k][ty * 4]);
      float4 b4 = *reinterpret_cast<const float4*>(&Bs[k][tx * 4]);
      float ar[4] = {a4.x, a4.y, a4.z, a4.w};
      float br[4] = {b4.x, b4.y, b4.z, b4.w};
      #pragma unroll
      for (int i = 0; i < 4; ++i)
        #pragma unroll
        for (int j = 0; j < 4; ++j)
          acc[i][j] += ar[i] * br[j];
    }
  }

  #pragma unroll
  for (int j = 0; j < 4; ++j) {
    int n = n0 + tx * 4 + j;
    float bb = bias[n];
    #pragma unroll
    for (int i = 0; i < 4; ++i) {
      int m = m0 + ty * 4 + i;
      int b = m & 63, t = m >> 6;
      out[((size_t)b * Tn + t) * Cn + n] = acc[i][j] + bb;
    }
  }
}

// ---------------------------------------------------------------------------
// MFMA W-stationary persistent LSTM: tagged records + sentinel detect.
// 128 blocks x 512 threads. Block (bg=bid>>5, hg=bid&31): batches [bg*16,+16),
// h-cols [hg*32,+32). W fp16 fragments (32 x v8h) in regs, loaded once.
//
// Producer (end of step t): (a) plain cached hs16 stores (FC input, off
// critical path), (b) 128 tagged 16B records {8B h payload, 0, tag=0x4000+t}
// via fire-and-forget sc0 sc1 stores — NO vmcnt drain, (c) one sentinel
// dword to the per-(t,bg) 128B flag line — also undrained.
// Consumer (step t+1): poll sentinel line (32 lanes, ONE line — cheap like
// R7), then ONE validating sweep of its own 128B record line (8x16B, tags
// checked in-register; rare straggler records retried in-loop). Tag-visible
// => payload-visible (16B store atomicity at the coherence point).
// Ping-pong slots by t&1; skew <= 2 enforced by the sentinel chain (a block
// reaches t+2 stores only after all blocks validated their t sweeps).
// Replay/poison safe: per-t exact flags + xbuf memset each call; tags
// 0x4000..0x41FF unreachable by |h|<1 fp16 payloads.
// ---------------------------------------------------------------------------
__global__ __launch_bounds__(512, 2) void lstm_mfma(
    const int* __restrict__ x,        // [B, T]
    const float* __restrict__ Whh,    // [4H, H] fp32
    const float* __restrict__ proj,   // [C, 4H] incl. both biases
    _Float16* __restrict__ hs16,      // [T, B, H] fp16, FC input (plain stores)
    char* __restrict__ xbuf,          // [2][4][32][128] x 16B tagged records
    int* __restrict__ flags)          // [Tn][4][32] sentinel dwords
{
  __shared__ __align__(16) char hT[32768];     // A-tile, fragment-linear
  __shared__ float gbuf[128 * 21];             // gate exchange, stride 21
  __shared__ _Float16 hstage[512];             // 16 x 32 fp16 h repack

  const int tid = threadIdx.x;
  const int bid = blockIdx.x;
  const int bg = bid >> 5, hg = bid & 31;
  const int b0 = bg * 16;

  const int w = tid >> 6, l = tid & 63;
  const int q = w >> 2, g = w & 3;
  const int mrow = l & 15;                     // B col in tile / A row
  const int kseg = l >> 4;                     // k-segment 0..3

  // ---- one-time W preload: fp32 -> fp16 fragments
  v8h wv[32];
  {
    const float* wr = Whh + (size_t)(g * Hn + hg * 32 + q * 16 + mrow) * Hn + kseg * 8;
    #pragma unroll
    for (int kk = 0; kk < 32; ++kk) {
      const float* p = wr + kk * 32;
      float4 f0 = *(const float4*)p, f1 = *(const float4*)(p + 4);
      v8h h8;
      h8[0] = (_Float16)f0.x; h8[1] = (_Float16)f0.y;
      h8[2] = (_Float16)f0.z; h8[3] = (_Float16)f0.w;
      h8[4] = (_Float16)f1.x; h8[5] = (_Float16)f1.y;
      h8[6] = (_Float16)f1.z; h8[7] = (_Float16)f1.w;
      wv[kk] = h8;
    }
  }

  // elementwise mapping: thread owns (batch eb, hcol ehc)
  const int eb = tid >> 5, ehc = tid & 31;
  const int* xp = x + (size_t)(b0 + eb) * Tn;
  float cst = 0.f;

  // consumer: thread reads producer p=tid>>4, batch=tid&15, records 0..7
  const int csrc = (tid >> 4) * 2048 + (tid & 15) * 128;
  const int dbase = (tid >> 4) * 1024 + (tid & 15) * 16;

  for (int t = 0; t < Tn; ++t) {
    const int cls = xp[t];
    // proj prefetch: issued before the wait, lands during it
    const float* pb = proj + (size_t)cls * Gn + hg * 32 + ehc;
    float p0 = pb[0], p1 = pb[Hn], p2 = pb[2 * Hn], p3 = pb[3 * Hn];

    if (t > 0) {
      // ---- cheap detect: 32 lanes poll ONE sentinel line for (t-1, bg)
      if (tid < 32) {
        const int* fp = flags + ((size_t)(t - 1) * 4 + bg) * 32 + tid;
        int v;
        do {
          asm volatile(
            "global_load_dword %0, %1, off sc0 sc1\n\t"
            "s_waitcnt vmcnt(0)"
            : "=v"(v) : "v"(fp) : "memory");
        } while (v == 0);
      }
      __syncthreads();

      // ---- ONE validating sweep: 8x16B (own 128B record line)
      const unsigned tagv = 0x4000u + (unsigned)(t - 1);
      const char* pp = xbuf + (size_t)((t - 1) & 1) * 262144 + bg * 65536 + csrc;
      v4u r0, r1, r2, r3, r4, r5, r6, r7;
      for (;;) {
        asm volatile(
          "global_load_dwordx4 %0, %8, off sc0 sc1\n\t"
          "global_load_dwordx4 %1, %8, off offset:16 sc0 sc1\n\t"
          "global_load_dwordx4 %2, %8, off offset:32 sc0 sc1\n\t"
          "global_load_dwordx4 %3, %8, off offset:48 sc0 sc1\n\t"
          "global_load_dwordx4 %4, %8, off offset:64 sc0 sc1\n\t"
          "global_load_dwordx4 %5, %8, off offset:80 sc0 sc1\n\t"
          "global_load_dwordx4 %6, %8, off offset:96 sc0 sc1\n\t"
          "global_load_dwordx4 %7, %8, off offset:112 sc0 sc1\n\t"
          "s_waitcnt vmcnt(0)"
          : "=&v"(r0), "=&v"(r1), "=&v"(r2), "=&v"(r3),
            "=&v"(r4), "=&v"(r5), "=&v"(r6), "=&v"(r7)
          : "v"(pp) : "memory");
        unsigned m = ((r0.w >> 16) ^ tagv) | ((r1.w >> 16) ^ tagv)
                   | ((r2.w >> 16) ^ tagv) | ((r3.w >> 16) ^ tagv)
                   | ((r4.w >> 16) ^ tagv) | ((r5.w >> 16) ^ tagv)
                   | ((r6.w >> 16) ^ tagv) | ((r7.w >> 16) ^ tagv);
        if (m == 0u) break;   // stragglers only; sentinel makes this ~1 pass
      }
      // scatter payloads (8B each) into the fragment-linear A-tile
      v4u rr[8] = {r0, r1, r2, r3, r4, r5, r6, r7};
      #pragma unroll
      for (int i = 0; i < 8; ++i) {
        *(unsigned long long*)(hT + dbase + (i >> 1) * 256 + (i & 1) * 8)
          = ((unsigned long long)rr[i].y << 32) | (unsigned long long)rr[i].x;
      }
    }
    __syncthreads();

    v4f acc0 = {0.f, 0.f, 0.f, 0.f};
    v4f acc1 = {0.f, 0.f, 0.f, 0.f};
    if (t > 0) {
      #pragma unroll
      for (int kk = 0; kk < 32; kk += 2) {
        v8h a0 = *(const v8h*)(hT + kk * 1024 + l * 16);
        v8h a1 = *(const v8h*)(hT + (kk + 1) * 1024 + l * 16);
        acc0 = __builtin_amdgcn_mfma_f32_16x16x32_f16(a0, wv[kk], acc0, 0, 0, 0);
        acc1 = __builtin_amdgcn_mfma_f32_16x16x32_f16(a1, wv[kk + 1], acc1, 0, 0, 0);
      }
    }

    // D frag: col = l&15 (hc within q-half), row = 4*kseg + r (batch)
    #pragma unroll
    for (int r = 0; r < 4; ++r)
      gbuf[(g * 32 + q * 16 + mrow) * 21 + kseg * 4 + r] = acc0[r] + acc1[r];
    __syncthreads();

    // elementwise: all 512 threads, one (batch, hc) each
    {
      float g0 = gbuf[(0 * 32 + ehc) * 21 + eb] + p0;
      float g1 = gbuf[(1 * 32 + ehc) * 21 + eb] + p1;
      float g2 = gbuf[(2 * 32 + ehc) * 21 + eb] + p2;
      float g3 = gbuf[(3 * 32 + ehc) * 21 + eb] + p3;
      float ig = sigmoidf_(g0), fg = sigmoidf_(g1);
      float gg = tanhf(g2),     og = sigmoidf_(g3);
      cst = fg * cst + ig * gg;
      hstage[eb * 32 + ehc] = (_Float16)(og * tanhf(cst));
    }
    __syncthreads();

    // (a) hs16 for the FC GEMM: plain cached stores, off critical path
    if (tid < 64) {
      const int b = tid >> 2, part = tid & 3;
      *(v4f*)(hs16 + ((size_t)t * Bn + b0 + b) * Hn + hg * 32 + part * 8)
        = *(const v4f*)(hstage + b * 32 + part * 8);
    }
    // (b) tagged exchange records: fire-and-forget 16B stores, NO drain
    if (tid < 128) {
      const int batch = tid >> 3, cg = tid & 7;
      unsigned long long d =
          *(const unsigned long long*)(hstage + batch * 32 + cg * 4);
      v4u val;
      val.x = (unsigned)d;
      val.y = (unsigned)(d >> 32);
      val.z = 0u;
      val.w = (0x4000u + (unsigned)t) << 16;
      char* dst = xbuf + (size_t)(t & 1) * 262144 + bg * 65536
                + hg * 2048 + tid * 16;
      asm volatile("global_store_dwordx4 %0, %1, off sc0 sc1"
                   :: "v"(dst), "v"(val) : "memory");
    }
    // (c) sentinel dword: also undrained; consumers validate via record tags
    if (tid == 0) {
      int one = 1;
      int* fq = flags + ((size_t)t * 4 + bg) * 32 + hg;
      asm volatile("global_store_dword %0, %1, off sc0 sc1"
                   :: "v"(fq), "v"(one) : "memory");
    }
    // hT/hstage reuse next step is ordered by the poll + __syncthreads chain.
  }
}

// ---------------------------------------------------------------------------
extern "C" void kernel_launch(void* const* d_in, const int* in_sizes, int n_in,
                              void* d_out, int out_size, void* d_ws, size_t ws_size,
                              hipStream_t stream) {
  const int*   x     = (const int*)  d_in[0];
  const float* embed = (const float*)d_in[1];
  const float* Wih   = (const float*)d_in[2];
  const float* Whh   = (const float*)d_in[3];
  const float* bih   = (const float*)d_in[4];
  const float* bhh   = (const float*)d_in[5];
  const float* fcW   = (const float*)d_in[6];
  const float* fcb   = (const float*)d_in[7];
  float* out = (float*)d_out;

  char* ws = (char*)d_ws;
  const size_t xbufBytes = 524288;                                     // 512 KB
  const size_t flagBytes = (size_t)Tn * 4 * 32 * 4;                    // 256 KB
  const size_t projBytes = (size_t)Cn * Gn * sizeof(float);            // 4 MB
  const size_t hsBytes   = (size_t)Tn * Bn * Hn * sizeof(_Float16);    // 64 MB
  const size_t need = xbufBytes + flagBytes + projBytes + hsBytes;
  if (ws_size < need) {
    hipMemsetAsync(d_out, 0, (size_t)out_size * sizeof(float), stream);
    return;
  }
  int*       flags = (int*)(ws + xbufBytes);
  float*     proj  = (float*)(ws + xbufBytes + flagBytes);
  _Float16*  hs16  = (_Float16*)(ws + xbufBytes + flagBytes + projBytes);

  // clear records + sentinels every call: no stale tag/flag can match
  hipMemsetAsync(d_ws, 0, xbufBytes + flagBytes, stream);

  // 1) proj[cls, 4H] = embed[cls,:] @ W_ih^T + b_ih + b_hh
  dim3 g1(Cn / 64, Gn / 64);   // (4, 64)
  gemm_tt<<<g1, 256, 0, stream>>>(embed, Wih, bih, bhh, proj, Cn, Gn, En);

  // 2) MFMA persistent recurrence (tagged records + sentinel detect)
  lstm_mfma<<<128, 512, 0, stream>>>(x, Whh, proj, hs16, ws, flags);

  // 3) out[b,t,:] = hs16[t,b,:] @ fc_W^T + fc_b
  dim3 g3((Bn * Tn) / 64, Cn / 64);  // (512, 4)
  gemm_fc<<<g3, 256, 0, stream>>>(hs16, fcW, fcb, out);
}

// Round 11
// 1991.681 us; speedup vs baseline: 1.8013x; 1.4377x over previous
//
#include <hip/hip_runtime.h>
#include <math.h>

#define DEV_INLINE __device__ __forceinline__

static constexpr int Bn = 64;     // batch
static constexpr int Tn = 512;    // time
static constexpr int En = 512;    // embed
static constexpr int Hn = 1024;   // hidden
static constexpr int Cn = 256;    // classes
static constexpr int Gn = 4 * Hn; // 4096 gates

typedef float v4f __attribute__((ext_vector_type(4)));
typedef _Float16 v8h __attribute__((ext_vector_type(8)));

DEV_INLINE float sigmoidf_(float v) { return 1.f / (1.f + __expf(-v)); }

// ---------------------------------------------------------------------------
// fp32 tiled GEMM:  C[M,N] = A[M,K] * B[N,K]^T + bias1[n] (+bias2[n])
// (used for proj = embed @ W_ih^T + b_ih + b_hh)
// ---------------------------------------------------------------------------
__global__ __launch_bounds__(256) void gemm_tt(
    const float* __restrict__ A, const float* __restrict__ Bm,
    const float* __restrict__ bias1, const float* __restrict__ bias2,
    float* __restrict__ Cm, int M, int N, int K)
{
  constexpr int KC = 32;
  __shared__ float As[KC][68];
  __shared__ float Bs[KC][68];
  const int tid = threadIdx.x;
  const int tx = tid & 15, ty = tid >> 4;
  const int m0 = blockIdx.x * 64, n0 = blockIdx.y * 64;

  float acc[4][4] = {};

  for (int k0 = 0; k0 < K; k0 += KC) {
    __syncthreads();
    #pragma unroll
    for (int j = 0; j < 2; ++j) {
      int f = tid + j * 256;
      int row = f >> 3;
      int c4 = f & 7;
      float4 va = *reinterpret_cast<const float4*>(&A[(size_t)(m0 + row) * K + k0 + c4 * 4]);
      As[c4 * 4 + 0][row] = va.x; As[c4 * 4 + 1][row] = va.y;
      As[c4 * 4 + 2][row] = va.z; As[c4 * 4 + 3][row] = va.w;
      float4 vb = *reinterpret_cast<const float4*>(&Bm[(size_t)(n0 + row) * K + k0 + c4 * 4]);
      Bs[c4 * 4 + 0][row] = vb.x; Bs[c4 * 4 + 1][row] = vb.y;
      Bs[c4 * 4 + 2][row] = vb.z; Bs[c4 * 4 + 3][row] = vb.w;
    }
    __syncthreads();
    #pragma unroll
    for (int k = 0; k < KC; ++k) {
      float4 a4 = *reinterpret_cast<const float4*>(&As[k][ty * 4]);
      float4 b4 = *reinterpret_cast<const float4*>(&Bs[k][tx * 4]);
      float ar[4] = {a4.x, a4.y, a4.z, a4.w};
      float br[4] = {b4.x, b4.y, b4.z, b4.w};
      #pragma unroll
      for (int i = 0; i < 4; ++i)
        #pragma unroll
        for (int j = 0; j < 4; ++j)
          acc[i][j] += ar[i] * br[j];
    }
  }

  #pragma unroll
  for (int j = 0; j < 4; ++j) {
    int n = n0 + tx * 4 + j;
    float bb = bias1[n];
    if (bias2) bb += bias2[n];
    #pragma unroll
    for (int i = 0; i < 4; ++i)
      Cm[(size_t)(m0 + ty * 4 + i) * N + n] = acc[i][j] + bb;
  }
}

// ---------------------------------------------------------------------------
// fcW fp32 -> fp16 convert (row-major [256][1024])
// ---------------------------------------------------------------------------
__global__ __launch_bounds__(256) void cvt_fcw(
    const float* __restrict__ fcW, _Float16* __restrict__ fcW16)
{
  const int idx = (blockIdx.x * 256 + threadIdx.x) * 8;   // 128 blocks cover 262144
  float4 f0 = *(const float4*)(fcW + idx);
  float4 f1 = *(const float4*)(fcW + idx + 4);
  v8h h8;
  h8[0] = (_Float16)f0.x; h8[1] = (_Float16)f0.y;
  h8[2] = (_Float16)f0.z; h8[3] = (_Float16)f0.w;
  h8[4] = (_Float16)f1.x; h8[5] = (_Float16)f1.y;
  h8[6] = (_Float16)f1.z; h8[7] = (_Float16)f1.w;
  *(v8h*)(fcW16 + idx) = h8;
}

// ---------------------------------------------------------------------------
// Fused persistent kernel, 256 blocks x 512 threads.
//
// Blocks 0..127 — LSTM (R7 exchange protocol, verified):
//   Block (bg=bid>>5, hg=bid&31): batches [bg*16,+16), h-cols [hg*32,+32).
//   NEW vs R7: MFMA operand swap — acc = mfma(A=W_frag, B=h_frag, acc) with
//   the wave's 16 A-rows arranged as m = hcolLocal*4 + gate. D (col=l&15=
//   batch, row=4*kseg+r) then gives each thread ALL 4 gates of its
//   (batch=l&15, hcol=hg*32+w*4+kseg) — elementwise runs on acc directly:
//   no gbuf LDS exchange, 2 fewer barriers, no stride-21 conflicts.
//   hT staging / srcoff / h-store / flag protocol byte-identical to R7.
//
// Blocks 128..255 — FC consumers:
//   Unit (t, bg) = out[b in bg][t][:] = hs16[t,b,:] @ fcW^T + fcb.
//   fid handles units {j*128+fid}: poll flag line (t,bg) with sleep backoff,
//   stage hs16 tile (same srcoff path, sc0 sc1), per wave 2 class-tiles
//   (clsbase = w*32 + nt*16): acc = mfma(A=fcW16 rows, B=h, acc) over 32 kk.
//   D row=class-in-tile, col=batch; contiguous v4f out stores + fcb.
//   FC runs concurrently with LSTM on separate CUs; tail ~ 1 unit.
// ---------------------------------------------------------------------------
__global__ __launch_bounds__(512, 2) void lstm_fused(
    const int* __restrict__ x,        // [B, T]
    const float* __restrict__ Whh,    // [4H, H] fp32
    const float* __restrict__ proj,   // [C, 4H] incl. both biases
    _Float16* __restrict__ hs16,      // [T, B, H] fp16 exchange buffer
    int* __restrict__ flags,          // [Tn][4][32] dwords (128B lines)
    const _Float16* __restrict__ fcW16, // [256][1024] fp16
    const float* __restrict__ fcb,    // [256]
    float* __restrict__ out)          // [64][512][256] fp32
{
  __shared__ __align__(16) char hT[32768];     // staged h tile, fragment-linear
  __shared__ _Float16 hstage[512];             // 16 x 32 fp16 h repack

  const int tid = threadIdx.x;
  const int bid = blockIdx.x;

  const int w = tid >> 6, l = tid & 63;
  const int mrow = l & 15;                     // fragment row index
  const int kseg = l >> 4;                     // k-segment 0..3

  // staging source offset (shared by both paths): dest hT + tid*16 + i*8192
  // is fragment-linear [kk][kseg][batch-row]; swizzle lives in global src.
  const int srcoff = (tid & 15) * 2048 + ((tid >> 4) & 3) * 16 + (tid >> 6) * 64;

  if (bid < 128) {
    // =========================== LSTM path ===============================
    const int bg = bid >> 5, hg = bid & 31;
    const int b0 = bg * 16;

    // ---- W preload: lane's A-row m = l&15 maps to (gate = m&3,
    //      hcolLocal = w*4 + (m>>2)); k-range kseg*8 + kk*32 as before.
    v8h wv[32];
    {
      const float* wr = Whh
        + (size_t)((mrow & 3) * Hn + hg * 32 + w * 4 + (mrow >> 2)) * Hn
        + kseg * 8;
      #pragma unroll
      for (int kk = 0; kk < 32; ++kk) {
        const float* p = wr + kk * 32;
        float4 f0 = *(const float4*)p, f1 = *(const float4*)(p + 4);
        v8h h8;
        h8[0] = (_Float16)f0.x; h8[1] = (_Float16)f0.y;
        h8[2] = (_Float16)f0.z; h8[3] = (_Float16)f0.w;
        h8[4] = (_Float16)f1.x; h8[5] = (_Float16)f1.y;
        h8[6] = (_Float16)f1.z; h8[7] = (_Float16)f1.w;
        wv[kk] = h8;
      }
    }

    // thread's elementwise identity (from D-fragment): batch l&15, hcol w*4+kseg
    const int eb = mrow;                 // batch in group
    const int ehc = w * 4 + kseg;        // hcol local 0..31
    const int* xp = x + (size_t)(b0 + eb) * Tn;
    float cst = 0.f;

    for (int t = 0; t < Tn; ++t) {
      const int cls = xp[t];
      // proj prefetch: lands during the wait
      const float* pb = proj + (size_t)cls * Gn + hg * 32 + ehc;
      float p0 = pb[0], p1 = pb[Hn], p2 = pb[2 * Hn], p3 = pb[3 * Hn];

      if (t > 0) {
        if (tid < 32) {
          const int* fp = flags + ((size_t)(t - 1) * 4 + bg) * 32 + tid;
          int v;
          do {
            asm volatile(
              "global_load_dword %0, %1, off sc0 sc1\n\t"
              "s_waitcnt vmcnt(0)"
              : "=v"(v) : "v"(fp) : "memory");
          } while (v == 0);
        }
        __syncthreads();

        const char* src = (const char*)(hs16 + ((size_t)(t - 1) * Bn + b0) * Hn);
        const char* s0 = src + srcoff;
        v4f r0, r1, r2, r3;
        asm volatile(
          "global_load_dwordx4 %0, %4, off sc0 sc1\n\t"
          "global_load_dwordx4 %1, %5, off sc0 sc1\n\t"
          "global_load_dwordx4 %2, %6, off sc0 sc1\n\t"
          "global_load_dwordx4 %3, %7, off sc0 sc1\n\t"
          "s_waitcnt vmcnt(0)"
          : "=&v"(r0), "=&v"(r1), "=&v"(r2), "=&v"(r3)
          : "v"(s0), "v"(s0 + 512), "v"(s0 + 1024), "v"(s0 + 1536)
          : "memory");
        *(v4f*)(hT + tid * 16 +     0) = r0;
        *(v4f*)(hT + tid * 16 +  8192) = r1;
        *(v4f*)(hT + tid * 16 + 16384) = r2;
        *(v4f*)(hT + tid * 16 + 24576) = r3;
      }
      __syncthreads();

      v4f acc0 = {0.f, 0.f, 0.f, 0.f};
      v4f acc1 = {0.f, 0.f, 0.f, 0.f};
      if (t > 0) {
        #pragma unroll
        for (int kk = 0; kk < 32; kk += 2) {
          v8h a0 = *(const v8h*)(hT + kk * 1024 + l * 16);
          v8h a1 = *(const v8h*)(hT + (kk + 1) * 1024 + l * 16);
          // operand swap: A = W fragment, B = h fragment
          acc0 = __builtin_amdgcn_mfma_f32_16x16x32_f16(wv[kk], a0, acc0, 0, 0, 0);
          acc1 = __builtin_amdgcn_mfma_f32_16x16x32_f16(wv[kk + 1], a1, acc1, 0, 0, 0);
        }
      }

      // gates live in-register: acc[r] = gate r of (eb, ehc)
      {
        float g0 = acc0[0] + acc1[0] + p0;
        float g1 = acc0[1] + acc1[1] + p1;
        float g2 = acc0[2] + acc1[2] + p2;
        float g3 = acc0[3] + acc1[3] + p3;
        float ig = sigmoidf_(g0), fg = sigmoidf_(g1);
        float gg = tanhf(g2),     og = sigmoidf_(g3);
        cst = fg * cst + ig * gg;
        hstage[eb * 32 + ehc] = (_Float16)(og * tanhf(cst));
      }
      __syncthreads();

      if (tid < 64) {
        // 16B coherent stores; wave-0 vmcnt(0) drains before flag publish
        const int b = tid >> 2, part = tid & 3;
        v4f v = *(const v4f*)(hstage + b * 32 + part * 8);
        _Float16* dp = hs16 + ((size_t)t * Bn + b0 + b) * Hn + hg * 32 + part * 8;
        asm volatile(
          "global_store_dwordx4 %0, %1, off sc0 sc1\n\t"
          "s_waitcnt vmcnt(0)"
          :: "v"(dp), "v"(v) : "memory");
        if (tid == 0) {
          int one = 1;
          int* fq = flags + ((size_t)t * 4 + bg) * 32 + hg;
          asm volatile(
            "global_store_dword %0, %1, off sc0 sc1\n\t"
            "s_waitcnt vmcnt(0)"
            :: "v"(fq), "v"(one) : "memory");
        }
      }
      // hT reuse next step ordered by poll + __syncthreads chain.
    }
  } else {
    // ============================ FC path ================================
    const int fid = bid - 128;

    for (int j = 0; j < 16; ++j) {
      const int unit = j * 128 + fid;          // 0..2047
      const int t = unit >> 2, bgf = unit & 3;
      const int b0f = bgf * 16;

      // wait for all 32 producers of (t, bgf); sleep backoff (latency-tolerant)
      if (tid < 32) {
        const int* fp = flags + ((size_t)t * 4 + bgf) * 32 + tid;
        int v;
        for (;;) {
          asm volatile(
            "global_load_dword %0, %1, off sc0 sc1\n\t"
            "s_waitcnt vmcnt(0)"
            : "=v"(v) : "v"(fp) : "memory");
          if (v != 0) break;
          __builtin_amdgcn_s_sleep(16);
        }
      }
      __syncthreads();   // also orders prev unit's hT reads before restage

      // stage hs16[t][b0f..+16][:] -> hT (identical fragment-linear path)
      {
        const char* src = (const char*)(hs16 + ((size_t)t * Bn + b0f) * Hn);
        const char* s0 = src + srcoff;
        v4f r0, r1, r2, r3;
        asm volatile(
          "global_load_dwordx4 %0, %4, off sc0 sc1\n\t"
          "global_load_dwordx4 %1, %5, off sc0 sc1\n\t"
          "global_load_dwordx4 %2, %6, off sc0 sc1\n\t"
          "global_load_dwordx4 %3, %7, off sc0 sc1\n\t"
          "s_waitcnt vmcnt(0)"
          : "=&v"(r0), "=&v"(r1), "=&v"(r2), "=&v"(r3)
          : "v"(s0), "v"(s0 + 512), "v"(s0 + 1024), "v"(s0 + 1536)
          : "memory");
        *(v4f*)(hT + tid * 16 +     0) = r0;
        *(v4f*)(hT + tid * 16 +  8192) = r1;
        *(v4f*)(hT + tid * 16 + 16384) = r2;
        *(v4f*)(hT + tid * 16 + 24576) = r3;
      }
      __syncthreads();

      // wave w covers classes [w*32, +32) as 2 tiles of 16
      #pragma unroll
      for (int nt = 0; nt < 2; ++nt) {
        const int clsbase = w * 32 + nt * 16;
        v4f acc = {0.f, 0.f, 0.f, 0.f};
        const _Float16* ab = fcW16 + (size_t)(clsbase + mrow) * Hn + kseg * 8;
        #pragma unroll
        for (int kk = 0; kk < 32; ++kk) {
          v8h af = *(const v8h*)(ab + kk * 32);
          v8h bf = *(const v8h*)(hT + kk * 1024 + l * 16);
          acc = __builtin_amdgcn_mfma_f32_16x16x32_f16(af, bf, acc, 0, 0, 0);
        }
        // D: row = 4*kseg + r = class-in-tile, col = l&15 = batch
        v4f b4 = *(const v4f*)(fcb + clsbase + kseg * 4);
        v4f res = {acc[0] + b4[0], acc[1] + b4[1], acc[2] + b4[2], acc[3] + b4[3]};
        float* op = out + ((size_t)(b0f + mrow) * Tn + t) * Cn + clsbase + kseg * 4;
        *(v4f*)op = res;
      }
    }
  }
}

// ---------------------------------------------------------------------------
extern "C" void kernel_launch(void* const* d_in, const int* in_sizes, int n_in,
                              void* d_out, int out_size, void* d_ws, size_t ws_size,
                              hipStream_t stream) {
  const int*   x     = (const int*)  d_in[0];
  const float* embed = (const float*)d_in[1];
  const float* Wih   = (const float*)d_in[2];
  const float* Whh   = (const float*)d_in[3];
  const float* bih   = (const float*)d_in[4];
  const float* bhh   = (const float*)d_in[5];
  const float* fcW   = (const float*)d_in[6];
  const float* fcb   = (const float*)d_in[7];
  float* out = (float*)d_out;

  char* ws = (char*)d_ws;
  const size_t flagBytes = (size_t)Tn * 4 * 32 * 4;                    // 256 KB
  const size_t projBytes = (size_t)Cn * Gn * sizeof(float);            // 4 MB
  const size_t hsBytes   = (size_t)Tn * Bn * Hn * sizeof(_Float16);    // 64 MB
  const size_t fw16Bytes = (size_t)Cn * Hn * sizeof(_Float16);         // 512 KB
  const size_t need = flagBytes + projBytes + hsBytes + fw16Bytes;
  if (ws_size < need) {
    hipMemsetAsync(d_out, 0, (size_t)out_size * sizeof(float), stream);
    return;
  }
  float*     proj  = (float*)(ws + flagBytes);
  _Float16*  hs16  = (_Float16*)(ws + flagBytes + projBytes);
  _Float16*  fcW16 = (_Float16*)(ws + flagBytes + projBytes + hsBytes);

  // zero flags every call (graph-capture-safe async memset)
  hipMemsetAsync(d_ws, 0, flagBytes, stream);

  // 0) fcW -> fp16
  cvt_fcw<<<128, 256, 0, stream>>>(fcW, fcW16);

  // 1) proj[cls, 4H] = embed[cls,:] @ W_ih^T + b_ih + b_hh
  dim3 g1(Cn / 64, Gn / 64);   // (4, 64)
  gemm_tt<<<g1, 256, 0, stream>>>(embed, Wih, bih, bhh, proj, Cn, Gn, En);

  // 2) fused persistent LSTM (blocks 0-127) + streaming FC (blocks 128-255)
  lstm_fused<<<256, 512, 0, stream>>>(x, Whh, proj, hs16, (int*)d_ws,
                                      fcW16, fcb, out);
}

// Round 12
// 1975.628 us; speedup vs baseline: 1.8160x; 1.0081x over previous
//
#include <hip/hip_runtime.h>
#include <math.h>

#define DEV_INLINE __device__ __forceinline__

static constexpr int Bn = 64;     // batch
static constexpr int Tn = 512;    // time
static constexpr int En = 512;    // embed
static constexpr int Hn = 1024;   // hidden
static constexpr int Cn = 256;    // classes
static constexpr int Gn = 4 * Hn; // 4096 gates

typedef float v4f __attribute__((ext_vector_type(4)));
typedef _Float16 v8h __attribute__((ext_vector_type(8)));

DEV_INLINE float sigmoidf_(float v) { return 1.f / (1.f + __expf(-v)); }

// ---------------------------------------------------------------------------
// fp32 tiled GEMM:  C[M,N] = A[M,K] * B[N,K]^T + bias1[n] (+bias2[n])
// (used for proj = embed @ W_ih^T + b_ih + b_hh)
// ---------------------------------------------------------------------------
__global__ __launch_bounds__(256) void gemm_tt(
    const float* __restrict__ A, const float* __restrict__ Bm,
    const float* __restrict__ bias1, const float* __restrict__ bias2,
    float* __restrict__ Cm, int M, int N, int K)
{
  constexpr int KC = 32;
  __shared__ float As[KC][68];
  __shared__ float Bs[KC][68];
  const int tid = threadIdx.x;
  const int tx = tid & 15, ty = tid >> 4;
  const int m0 = blockIdx.x * 64, n0 = blockIdx.y * 64;

  float acc[4][4] = {};

  for (int k0 = 0; k0 < K; k0 += KC) {
    __syncthreads();
    #pragma unroll
    for (int j = 0; j < 2; ++j) {
      int f = tid + j * 256;
      int row = f >> 3;
      int c4 = f & 7;
      float4 va = *reinterpret_cast<const float4*>(&A[(size_t)(m0 + row) * K + k0 + c4 * 4]);
      As[c4 * 4 + 0][row] = va.x; As[c4 * 4 + 1][row] = va.y;
      As[c4 * 4 + 2][row] = va.z; As[c4 * 4 + 3][row] = va.w;
      float4 vb = *reinterpret_cast<const float4*>(&Bm[(size_t)(n0 + row) * K + k0 + c4 * 4]);
      Bs[c4 * 4 + 0][row] = vb.x; Bs[c4 * 4 + 1][row] = vb.y;
      Bs[c4 * 4 + 2][row] = vb.z; Bs[c4 * 4 + 3][row] = vb.w;
    }
    __syncthreads();
    #pragma unroll
    for (int k = 0; k < KC; ++k) {
      float4 a4 = *reinterpret_cast<const float4*>(&As[k][ty * 4]);
      float4 b4 = *reinterpret_cast<const float4*>(&Bs[k][tx * 4]);
      float ar[4] = {a4.x, a4.y, a4.z, a4.w};
      float br[4] = {b4.x, b4.y, b4.z, b4.w};
      #pragma unroll
      for (int i = 0; i < 4; ++i)
        #pragma unroll
        for (int j = 0; j < 4; ++j)
          acc[i][j] += ar[i] * br[j];
    }
  }

  #pragma unroll
  for (int j = 0; j < 4; ++j) {
    int n = n0 + tx * 4 + j;
    float bb = bias1[n];
    if (bias2) bb += bias2[n];
    #pragma unroll
    for (int i = 0; i < 4; ++i)
      Cm[(size_t)(m0 + ty * 4 + i) * N + n] = acc[i][j] + bb;
  }
}

// ---------------------------------------------------------------------------
// fcW fp32 -> fp16 convert (row-major [256][1024])
// ---------------------------------------------------------------------------
__global__ __launch_bounds__(256) void cvt_fcw(
    const float* __restrict__ fcW, _Float16* __restrict__ fcW16)
{
  const int idx = (blockIdx.x * 256 + threadIdx.x) * 8;   // 128 blocks cover 262144
  float4 f0 = *(const float4*)(fcW + idx);
  float4 f1 = *(const float4*)(fcW + idx + 4);
  v8h h8;
  h8[0] = (_Float16)f0.x; h8[1] = (_Float16)f0.y;
  h8[2] = (_Float16)f0.z; h8[3] = (_Float16)f0.w;
  h8[4] = (_Float16)f1.x; h8[5] = (_Float16)f1.y;
  h8[6] = (_Float16)f1.z; h8[7] = (_Float16)f1.w;
  *(v8h*)(fcW16 + idx) = h8;
}

// ---------------------------------------------------------------------------
// Fused persistent kernel, 256 blocks x 512 threads.
//
// Blocks 0..127 — LSTM:
//   Block (bg=bid>>5, hg=bid&31): batches [bg*16,+16), h-cols [hg*32,+32).
//   In-register gates: acc = mfma(A=W_frag rows m=hcolLocal*4+gate, B=h_frag);
//   D (col=batch, row=4*kseg+r) gives each lane all 4 gates of its
//   (batch=l&15, hcol=w*4+kseg) — no LDS gate exchange.
//   TWO-PHASE split-K staging pipeline: h cols 0-511 are produced by hg
//   0-15, cols 512-1023 by hg 16-31.  pollA(flags 0-15) -> issue loads
//   r0,r1 -> pollB(flags 16-31, overlaps r0,r1 flight) -> issue r2,r3 ->
//   vmcnt(2) -> LDS-write A -> MFMA kk0-15 (r2,r3 in flight underneath)
//   -> vmcnt(0) -> LDS-write B (disjoint) -> MFMA kk16-31.
//   Producer side identical to R7: wave-0 sc0 sc1 h stores, vmcnt drain,
//   then flag dword; per-(t,bg) 128B flag lines, memset'd each call.
//
// Blocks 128..255 — FC consumers (out[b][t][:] = hs16[t,b,:]@fcW^T+fcb):
//   unit (t,bg) = j*128+fid; poll full flag line with s_sleep(64) backoff
//   (latency-tolerant, 4x less flag-line pressure than R11), stage, 2
//   class-tiles per wave via mfma(A=fcW16, B=h), v4f out stores.
// ---------------------------------------------------------------------------
__global__ __launch_bounds__(512, 2) void lstm_fused(
    const int* __restrict__ x,        // [B, T]
    const float* __restrict__ Whh,    // [4H, H] fp32
    const float* __restrict__ proj,   // [C, 4H] incl. both biases
    _Float16* __restrict__ hs16,      // [T, B, H] fp16 exchange buffer
    int* __restrict__ flags,          // [Tn][4][32] dwords (128B lines)
    const _Float16* __restrict__ fcW16, // [256][1024] fp16
    const float* __restrict__ fcb,    // [256]
    float* __restrict__ out)          // [64][512][256] fp32
{
  __shared__ __align__(16) char hT[32768];     // staged h tile, fragment-linear
  __shared__ _Float16 hstage[16 * 40];         // stride 40: 8-bank spread,
                                               // 80B rows (16B-aligned reads)

  const int tid = threadIdx.x;
  const int bid = blockIdx.x;

  const int w = tid >> 6, l = tid & 63;
  const int mrow = l & 15;                     // fragment row index
  const int kseg = l >> 4;                     // k-segment 0..3

  // staging source offset: dest hT + tid*16 + i*8192 is fragment-linear
  // [kk][kseg][batch-row]; swizzle lives in the global source address.
  const int srcoff = (tid & 15) * 2048 + ((tid >> 4) & 3) * 16 + (tid >> 6) * 64;

  if (bid < 128) {
    // =========================== LSTM path ===============================
    const int bg = bid >> 5, hg = bid & 31;
    const int b0 = bg * 16;

    // ---- W preload: lane's A-row m = l&15 -> (gate = m&3, hcolLocal =
    //      w*4 + (m>>2)); k-range kseg*8 + kk*32.
    v8h wv[32];
    {
      const float* wr = Whh
        + (size_t)((mrow & 3) * Hn + hg * 32 + w * 4 + (mrow >> 2)) * Hn
        + kseg * 8;
      #pragma unroll
      for (int kk = 0; kk < 32; ++kk) {
        const float* p = wr + kk * 32;
        float4 f0 = *(const float4*)p, f1 = *(const float4*)(p + 4);
        v8h h8;
        h8[0] = (_Float16)f0.x; h8[1] = (_Float16)f0.y;
        h8[2] = (_Float16)f0.z; h8[3] = (_Float16)f0.w;
        h8[4] = (_Float16)f1.x; h8[5] = (_Float16)f1.y;
        h8[6] = (_Float16)f1.z; h8[7] = (_Float16)f1.w;
        wv[kk] = h8;
      }
    }

    // elementwise identity (from D-fragment): batch l&15, hcol w*4+kseg
    const int eb = mrow;
    const int ehc = w * 4 + kseg;
    const int* xp = x + (size_t)(b0 + eb) * Tn;
    float cst = 0.f;

    for (int t = 0; t < Tn; ++t) {
      const int cls = xp[t];
      const float* pb = proj + (size_t)cls * Gn + hg * 32 + ehc;
      float p0 = pb[0], p1 = pb[Hn], p2 = pb[2 * Hn], p3 = pb[3 * Hn];

      v4f acc0 = {0.f, 0.f, 0.f, 0.f};
      v4f acc1 = {0.f, 0.f, 0.f, 0.f};

      if (t > 0) {
        const char* s0 = (const char*)(hs16 + ((size_t)(t - 1) * Bn + b0) * Hn)
                       + srcoff;
        // ---- phase A detect: cols 0-511 (producers hg 0-15)
        if (tid < 16) {
          const int* fp = flags + ((size_t)(t - 1) * 4 + bg) * 32 + tid;
          int v;
          do {
            asm volatile(
              "global_load_dword %0, %1, off sc0 sc1\n\t"
              "s_waitcnt vmcnt(0)"
              : "=v"(v) : "v"(fp) : "memory");
          } while (v == 0);
        }
        __syncthreads();
        // issue A loads, no wait
        v4f r0, r1, r2, r3;
        asm volatile(
          "global_load_dwordx4 %0, %2, off sc0 sc1\n\t"
          "global_load_dwordx4 %1, %3, off sc0 sc1"
          : "=&v"(r0), "=&v"(r1)
          : "v"(s0), "v"(s0 + 512) : "memory");
        // ---- phase B detect: cols 512-1023 (producers hg 16-31);
        //      overlaps the A loads' flight
        if (tid >= 16 && tid < 32) {
          const int* fp = flags + ((size_t)(t - 1) * 4 + bg) * 32 + tid;
          int v;
          do {
            asm volatile(
              "global_load_dword %0, %1, off sc0 sc1\n\t"
              "s_waitcnt vmcnt(0)"
              : "=v"(v) : "v"(fp) : "memory");
          } while (v == 0);
        }
        __syncthreads();
        // issue B loads, no wait
        asm volatile(
          "global_load_dwordx4 %0, %2, off sc0 sc1\n\t"
          "global_load_dwordx4 %1, %3, off sc0 sc1"
          : "=&v"(r2), "=&v"(r3)
          : "v"(s0 + 1024), "v"(s0 + 1536) : "memory");
        // wait A only (B stays in flight)
        asm volatile("s_waitcnt vmcnt(2)" ::: "memory");
        *(v4f*)(hT + tid * 16 +    0) = r0;
        *(v4f*)(hT + tid * 16 + 8192) = r1;
        __syncthreads();
        // MFMA over kk 0..15 while r2,r3 travel
        #pragma unroll
        for (int kk = 0; kk < 16; kk += 2) {
          v8h a0 = *(const v8h*)(hT + kk * 1024 + l * 16);
          v8h a1 = *(const v8h*)(hT + (kk + 1) * 1024 + l * 16);
          acc0 = __builtin_amdgcn_mfma_f32_16x16x32_f16(wv[kk], a0, acc0, 0, 0, 0);
          acc1 = __builtin_amdgcn_mfma_f32_16x16x32_f16(wv[kk + 1], a1, acc1, 0, 0, 0);
        }
        asm volatile("s_waitcnt vmcnt(0)" ::: "memory");
        *(v4f*)(hT + tid * 16 + 16384) = r2;   // disjoint from A region
        *(v4f*)(hT + tid * 16 + 24576) = r3;
        __syncthreads();
        #pragma unroll
        for (int kk = 16; kk < 32; kk += 2) {
          v8h a0 = *(const v8h*)(hT + kk * 1024 + l * 16);
          v8h a1 = *(const v8h*)(hT + (kk + 1) * 1024 + l * 16);
          acc0 = __builtin_amdgcn_mfma_f32_16x16x32_f16(wv[kk], a0, acc0, 0, 0, 0);
          acc1 = __builtin_amdgcn_mfma_f32_16x16x32_f16(wv[kk + 1], a1, acc1, 0, 0, 0);
        }
      }

      // gates in-register: acc[r] = gate r of (eb, ehc)
      {
        float g0 = acc0[0] + acc1[0] + p0;
        float g1 = acc0[1] + acc1[1] + p1;
        float g2 = acc0[2] + acc1[2] + p2;
        float g3 = acc0[3] + acc1[3] + p3;
        float ig = sigmoidf_(g0), fg = sigmoidf_(g1);
        float gg = tanhf(g2),     og = sigmoidf_(g3);
        cst = fg * cst + ig * gg;
        hstage[eb * 40 + ehc] = (_Float16)(og * tanhf(cst));
      }
      __syncthreads();

      if (tid < 64) {
        // 16B coherent stores; wave-0 vmcnt(0) drains before flag publish
        const int b = tid >> 2, part = tid & 3;
        v4f v = *(const v4f*)(hstage + b * 40 + part * 8);
        _Float16* dp = hs16 + ((size_t)t * Bn + b0 + b) * Hn + hg * 32 + part * 8;
        asm volatile(
          "global_store_dwordx4 %0, %1, off sc0 sc1\n\t"
          "s_waitcnt vmcnt(0)"
          :: "v"(dp), "v"(v) : "memory");
        if (tid == 0) {
          int one = 1;
          int* fq = flags + ((size_t)t * 4 + bg) * 32 + hg;
          asm volatile(
            "global_store_dword %0, %1, off sc0 sc1\n\t"
            "s_waitcnt vmcnt(0)"
            :: "v"(fq), "v"(one) : "memory");
        }
      }
      __syncthreads();   // hstage reuse next step
    }
  } else {
    // ============================ FC path ================================
    const int fid = bid - 128;

    for (int j = 0; j < 16; ++j) {
      const int unit = j * 128 + fid;          // 0..2047
      const int t = unit >> 2, bgf = unit & 3;
      const int b0f = bgf * 16;

      // wait for all 32 producers of (t, bgf); long sleep backoff
      if (tid < 32) {
        const int* fp = flags + ((size_t)t * 4 + bgf) * 32 + tid;
        int v;
        for (;;) {
          asm volatile(
            "global_load_dword %0, %1, off sc0 sc1\n\t"
            "s_waitcnt vmcnt(0)"
            : "=v"(v) : "v"(fp) : "memory");
          if (v != 0) break;
          __builtin_amdgcn_s_sleep(64);
        }
      }
      __syncthreads();   // also orders prev unit's hT reads before restage

      // stage hs16[t][b0f..+16][:] -> hT
      {
        const char* s0 = (const char*)(hs16 + ((size_t)t * Bn + b0f) * Hn)
                       + srcoff;
        v4f r0, r1, r2, r3;
        asm volatile(
          "global_load_dwordx4 %0, %4, off sc0 sc1\n\t"
          "global_load_dwordx4 %1, %5, off sc0 sc1\n\t"
          "global_load_dwordx4 %2, %6, off sc0 sc1\n\t"
          "global_load_dwordx4 %3, %7, off sc0 sc1\n\t"
          "s_waitcnt vmcnt(0)"
          : "=&v"(r0), "=&v"(r1), "=&v"(r2), "=&v"(r3)
          : "v"(s0), "v"(s0 + 512), "v"(s0 + 1024), "v"(s0 + 1536)
          : "memory");
        *(v4f*)(hT + tid * 16 +     0) = r0;
        *(v4f*)(hT + tid * 16 +  8192) = r1;
        *(v4f*)(hT + tid * 16 + 16384) = r2;
        *(v4f*)(hT + tid * 16 + 24576) = r3;
      }
      __syncthreads();

      // wave w covers classes [w*32, +32) as 2 tiles of 16
      #pragma unroll
      for (int nt = 0; nt < 2; ++nt) {
        const int clsbase = w * 32 + nt * 16;
        v4f acc = {0.f, 0.f, 0.f, 0.f};
        const _Float16* ab = fcW16 + (size_t)(clsbase + mrow) * Hn + kseg * 8;
        #pragma unroll
        for (int kk = 0; kk < 32; ++kk) {
          v8h af = *(const v8h*)(ab + kk * 32);
          v8h bf = *(const v8h*)(hT + kk * 1024 + l * 16);
          acc = __builtin_amdgcn_mfma_f32_16x16x32_f16(af, bf, acc, 0, 0, 0);
        }
        // D: row = 4*kseg + r = class-in-tile, col = l&15 = batch
        v4f b4 = *(const v4f*)(fcb + clsbase + kseg * 4);
        v4f res = {acc[0] + b4[0], acc[1] + b4[1], acc[2] + b4[2], acc[3] + b4[3]};
        float* op = out + ((size_t)(b0f + mrow) * Tn + t) * Cn + clsbase + kseg * 4;
        *(v4f*)op = res;
      }
    }
  }
}

// ---------------------------------------------------------------------------
extern "C" void kernel_launch(void* const* d_in, const int* in_sizes, int n_in,
                              void* d_out, int out_size, void* d_ws, size_t ws_size,
                              hipStream_t stream) {
  const int*   x     = (const int*)  d_in[0];
  const float* embed = (const float*)d_in[1];
  const float* Wih   = (const float*)d_in[2];
  const float* Whh   = (const float*)d_in[3];
  const float* bih   = (const float*)d_in[4];
  const float* bhh   = (const float*)d_in[5];
  const float* fcW   = (const float*)d_in[6];
  const float* fcb   = (const float*)d_in[7];
  float* out = (float*)d_out;

  char* ws = (char*)d_ws;
  const size_t flagBytes = (size_t)Tn * 4 * 32 * 4;                    // 256 KB
  const size_t projBytes = (size_t)Cn * Gn * sizeof(float);            // 4 MB
  const size_t hsBytes   = (size_t)Tn * Bn * Hn * sizeof(_Float16);    // 64 MB
  const size_t fw16Bytes = (size_t)Cn * Hn * sizeof(_Float16);         // 512 KB
  const size_t need = flagBytes + projBytes + hsBytes + fw16Bytes;
  if (ws_size < need) {
    hipMemsetAsync(d_out, 0, (size_t)out_size * sizeof(float), stream);
    return;
  }
  float*     proj  = (float*)(ws + flagBytes);
  _Float16*  hs16  = (_Float16*)(ws + flagBytes + projBytes);
  _Float16*  fcW16 = (_Float16*)(ws + flagBytes + projBytes + hsBytes);

  // zero flags every call (graph-capture-safe async memset)
  hipMemsetAsync(d_ws, 0, flagBytes, stream);

  // 0) fcW -> fp16
  cvt_fcw<<<128, 256, 0, stream>>>(fcW, fcW16);

  // 1) proj[cls, 4H] = embed[cls,:] @ W_ih^T + b_ih + b_hh
  dim3 g1(Cn / 64, Gn / 64);   // (4, 64)
  gemm_tt<<<g1, 256, 0, stream>>>(embed, Wih, bih, bhh, proj, Cn, Gn, En);

  // 2) fused persistent LSTM (blocks 0-127) + streaming FC (blocks 128-255)
  lstm_fused<<<256, 512, 0, stream>>>(x, Whh, proj, hs16, (int*)d_ws,
                                      fcW16, fcb, out);
}